// Round 1
// baseline (5215.423 us; speedup 1.0000x reference)
//
#include <hip/hip_runtime.h>

typedef unsigned short u16;
typedef unsigned int   u32;

typedef __bf16 bf16_t;
typedef bf16_t bf16x8 __attribute__((ext_vector_type(8)));
typedef float  f32x4  __attribute__((ext_vector_type(4)));
typedef u16    u16x8  __attribute__((ext_vector_type(8)));

__device__ __forceinline__ float bf2f(u16 u) { return __uint_as_float(((u32)u) << 16); }
__device__ __forceinline__ u16 f2bf(float f) {
  u32 u = __float_as_uint(f);
  u32 r = u + 0x7fffu + ((u >> 16) & 1u);
  return (u16)(r >> 16);
}

// ---------------- cast f32 -> bf16 ----------------
__global__ void k_cast_bf16(const float* __restrict__ in, u16* __restrict__ out, int n) {
  int i = blockIdx.x * blockDim.x + threadIdx.x;
  int stride = gridDim.x * blockDim.x;
  for (; i < n; i += stride) out[i] = f2bf(in[i]);
}

// ---------------- GEMM: C(MxN) = alpha * A(MxK) @ B(NxK)^T + beta*C ----------------
// A, B bf16 (row-major, K contiguous); C f32. M%64==0, N%64==0, K%64==0.
#define GBM 64
#define GBN 64
#define GBK 64

__global__ __launch_bounds__(256) void k_gemm_bt(
    const u16* __restrict__ A, const u16* __restrict__ B, float* __restrict__ C,
    int M, int N, int K, float alpha, int beta) {
  __shared__ u16 As[GBM][GBK + 8];  // stride 72 u16 = 144B (16B aligned, 2-way frag reads)
  __shared__ u16 Bs[GBN][GBK + 8];
  const int tid   = threadIdx.x;
  const int lane  = tid & 63;
  const int w     = tid >> 6;
  const int wm    = (w >> 1) * 32;
  const int wn    = (w & 1) * 32;
  const int row16 = lane & 15;
  const int quad  = lane >> 4;
  const int m0 = blockIdx.y * GBM;
  const int n0 = blockIdx.x * GBN;
  const int ldr = tid >> 2;        // 0..63
  const int ldc = (tid & 3) * 16;  // 0,16,32,48

  f32x4 acc[2][2] = {};

  for (int k0 = 0; k0 < K; k0 += GBK) {
    const u16* ga = A + (size_t)(m0 + ldr) * K + (k0 + ldc);
    const u16* gb = B + (size_t)(n0 + ldr) * K + (k0 + ldc);
    u16x8 a0 = *(const u16x8*)ga;
    u16x8 a1 = *(const u16x8*)(ga + 8);
    u16x8 b0 = *(const u16x8*)gb;
    u16x8 b1 = *(const u16x8*)(gb + 8);
    __syncthreads();  // protect previous tile's reads
    *(u16x8*)&As[ldr][ldc]     = a0;
    *(u16x8*)&As[ldr][ldc + 8] = a1;
    *(u16x8*)&Bs[ldr][ldc]     = b0;
    *(u16x8*)&Bs[ldr][ldc + 8] = b1;
    __syncthreads();
#pragma unroll
    for (int kk = 0; kk < GBK; kk += 32) {
      bf16x8 af0 = *(const bf16x8*)&As[wm + row16][kk + quad * 8];
      bf16x8 af1 = *(const bf16x8*)&As[wm + 16 + row16][kk + quad * 8];
      bf16x8 bg0 = *(const bf16x8*)&Bs[wn + row16][kk + quad * 8];
      bf16x8 bg1 = *(const bf16x8*)&Bs[wn + 16 + row16][kk + quad * 8];
      acc[0][0] = __builtin_amdgcn_mfma_f32_16x16x32_bf16(af0, bg0, acc[0][0], 0, 0, 0);
      acc[0][1] = __builtin_amdgcn_mfma_f32_16x16x32_bf16(af0, bg1, acc[0][1], 0, 0, 0);
      acc[1][0] = __builtin_amdgcn_mfma_f32_16x16x32_bf16(af1, bg0, acc[1][0], 0, 0, 0);
      acc[1][1] = __builtin_amdgcn_mfma_f32_16x16x32_bf16(af1, bg1, acc[1][1], 0, 0, 0);
    }
  }
#pragma unroll
  for (int tm = 0; tm < 2; ++tm)
#pragma unroll
    for (int tn = 0; tn < 2; ++tn) {
      int gm = m0 + wm + tm * 16 + quad * 4;
      int gn = n0 + wn + tn * 16 + row16;
#pragma unroll
      for (int r = 0; r < 4; ++r) {
        size_t idx = (size_t)(gm + r) * N + gn;
        float v = alpha * acc[tm][tn][r];
        if (beta) v += C[idx];
        C[idx] = v;
      }
    }
}

// ---------------- RoPE + split qkv ----------------
// qkv f32 (4096, 5120) -> qb (4096,24,128) bf16, kb (4096,8,128), vb (4096,8,128)
__global__ void k_rope_split(const float* __restrict__ qkv, const int* __restrict__ pos_ids,
                             u16* __restrict__ qb, u16* __restrict__ kb, u16* __restrict__ vb) {
  const int r  = blockIdx.x;   // 0..4095
  const int hh = blockIdx.y;   // 0..39: 0-23 q, 24-31 k, 32-39 v
  const int d  = threadIdx.x;  // 0..127
  const float pos = (float)pos_ids[r];
  const float* src;
  if (hh < 24)       src = qkv + (size_t)r * 5120 + hh * 128;
  else if (hh < 32)  src = qkv + (size_t)r * 5120 + 3072 + (hh - 24) * 128;
  else               src = qkv + (size_t)r * 5120 + 4096 + (hh - 32) * 128;
  float x = src[d];
  float outv;
  if (hh >= 32 || d >= 96) {
    outv = x;
  } else {
    int j = (d < 48) ? d : d - 48;
    float invf = powf(10000.0f, -(float)j * (1.0f / 48.0f));
    float e = pos * invf;
    float c = cosf(e), sn = sinf(e);
    if (d < 48) outv = x * c - src[d + 48] * sn;
    else        outv = x * c + src[d - 48] * sn;
  }
  u16 o = f2bf(outv);
  if (hh < 24)      qb[((size_t)r * 24 + hh) * 128 + d] = o;
  else if (hh < 32) kb[((size_t)r * 8 + (hh - 24)) * 128 + d] = o;
  else              vb[((size_t)r * 8 + (hh - 32)) * 128 + d] = o;
}

// ---------------- flash-style causal GQA attention ----------------
// grid (512, 48): x = q group of 4 rows (one per wave), y = b*24 + h. block 256.
__device__ __forceinline__ float wredmax(float v) {
#pragma unroll
  for (int o = 32; o > 0; o >>= 1) v = fmaxf(v, __shfl_xor(v, o));
  return v;
}
__device__ __forceinline__ float wredsum(float v) {
#pragma unroll
  for (int o = 32; o > 0; o >>= 1) v += __shfl_xor(v, o);
  return v;
}

__global__ __launch_bounds__(256) void k_attn(
    const u16* __restrict__ qb, const u16* __restrict__ kb, const u16* __restrict__ vb,
    u16* __restrict__ attnb) {
  __shared__ float Kt[128 * 66];  // [d][k], stride 66 -> 2-way (free) reads
  __shared__ u32   Vp[64 * 66];   // [k][d2] packed bf16 pair (d2, d2+64)
  __shared__ float qsh[4 * 128];

  const int tid  = threadIdx.x;
  const int lane = tid & 63;
  const int w    = tid >> 6;
  const int bh   = blockIdx.y;
  const int b    = bh / 24;
  const int h    = bh % 24;
  const int kvh  = h / 3;  // 24 q heads -> 8 kv heads, groups of 3
  const int q0   = blockIdx.x * 4;
  const int myq  = q0 + w;

  // stage the 4 q rows, pre-scaled by 1/sqrt(128)
  for (int e = tid; e < 512; e += 256) {
    int qw = e >> 7, d = e & 127;
    u16 uv = qb[(((size_t)(b * 2048 + q0 + qw)) * 24 + h) * 128 + d];
    qsh[qw * 128 + d] = bf2f(uv) * 0.08838834764831845f;
  }

  float m = -INFINITY, l = 0.f, o0 = 0.f, o1 = 0.f;
  const int ntiles = ((q0 + 3) >> 6) + 1;

  for (int t = 0; t < ntiles; ++t) {
    const int kbase = t * 64;
    __syncthreads();  // prior tile fully consumed (and qsh ready on t==0)
    // stage K transposed: 64 rows x 128 dims, 16B global loads
    for (int c = tid; c < 1024; c += 256) {
      int kk = c >> 4, d8 = (c & 15) * 8;
      const u16* krow = kb + ((size_t)(b * 2048 + kbase + kk) * 8 + kvh) * 128;
      u16x8 vk = *(const u16x8*)(krow + d8);
#pragma unroll
      for (int j = 0; j < 8; ++j) Kt[(d8 + j) * 66 + kk] = bf2f(vk[j]);
    }
    // stage V packed pairs (d2, d2+64)
    for (int c = tid; c < 512; c += 256) {
      int kk = c >> 3, d8 = (c & 7) * 8;
      const u16* vrow = vb + ((size_t)(b * 2048 + kbase + kk) * 8 + kvh) * 128;
      u16x8 lo = *(const u16x8*)(vrow + d8);
      u16x8 hi = *(const u16x8*)(vrow + d8 + 64);
#pragma unroll
      for (int j = 0; j < 8; ++j) Vp[kk * 66 + d8 + j] = (u32)lo[j] | ((u32)hi[j] << 16);
    }
    __syncthreads();

    if (myq >= kbase) {
      float acc = 0.f;
#pragma unroll 16
      for (int d = 0; d < 128; ++d) acc = fmaf(qsh[w * 128 + d], Kt[d * 66 + lane], acc);
      int kidx = kbase + lane;
      float s = (kidx <= myq) ? acc : -INFINITY;
      float mt = wredmax(s);
      float mnew = fmaxf(m, mt);
      float alphaf = __expf(m - mnew);  // m=-inf on first tile -> 0
      float p = __expf(s - mnew);       // s=-inf -> 0
      float ls = wredsum(p);
      l = l * alphaf + ls;
      m = mnew;
      o0 *= alphaf; o1 *= alphaf;
#pragma unroll
      for (int kk = 0; kk < 64; ++kk) {
        float pk = __shfl(p, kk);
        u32 vv = Vp[kk * 66 + lane];
        o0 = fmaf(pk, __uint_as_float(vv << 16), o0);
        o1 = fmaf(pk, __uint_as_float(vv & 0xffff0000u), o1);
      }
    }
  }
  float inv = 1.0f / l;
  size_t obase = ((size_t)(b * 2048 + myq)) * 3072 + h * 128;
  attnb[obase + lane]      = f2bf(o0 * inv);
  attnb[obase + lane + 64] = f2bf(o1 * inv);
}

// ---------------- workspace layout (bytes) ----------------
#define SZ_XB     ((size_t)4096 * 3072 * 2)   // 25165824
#define SZ_WQKVB  ((size_t)5120 * 3072 * 2)   // 31457280
#define SZ_AQKVB  ((size_t)256 * 3072 * 2)
#define SZ_BQKVB  ((size_t)5120 * 256 * 2)
#define SZ_WOB    ((size_t)3072 * 3072 * 2)
#define SZ_AOB    ((size_t)256 * 3072 * 2)
#define SZ_BOB    ((size_t)3072 * 256 * 2)
#define SZ_QKV    ((size_t)4096 * 5120 * 4)   // 83886080
#define SZ_TA     ((size_t)4096 * 256 * 4)
#define SZ_TAB    ((size_t)4096 * 256 * 2)

#define OFF_XB    ((size_t)0)
#define OFF_WQKVB (OFF_XB + SZ_XB)
#define OFF_AQKVB (OFF_WQKVB + SZ_WQKVB)
#define OFF_BQKVB (OFF_AQKVB + SZ_AQKVB)
#define OFF_WOB   (OFF_BQKVB + SZ_BQKVB)
#define OFF_AOB   (OFF_WOB + SZ_WOB)
#define OFF_BOB   (OFF_AOB + SZ_AOB)
#define OFF_QKV   (OFF_BOB + SZ_BOB)
#define OFF_TA    (OFF_QKV + SZ_QKV)
#define OFF_TAB   (OFF_TA + SZ_TA)
// overlays (lifetimes do not intersect):
#define OFF_QB    OFF_XB                       // 25165824 bytes, == SZ_XB
#define OFF_KB    OFF_WQKVB                    // 8388608
#define OFF_VB    (OFF_WQKVB + (size_t)8388608)
#define OFF_ATTNB OFF_QKV                      // 25165824, inside dead qkv
#define OFF_TO    (OFF_QKV + (size_t)25165824) // f32 4194304
#define OFF_TOB   (OFF_TO + (size_t)4194304)

static inline void launch_cast(const float* in, u16* out, int n, hipStream_t s) {
  int blocks = (n + 1023) / 1024;
  if (blocks > 8192) blocks = 8192;
  k_cast_bf16<<<blocks, 256, 0, s>>>(in, out, n);
}

extern "C" void kernel_launch(void* const* d_in, const int* in_sizes, int n_in,
                              void* d_out, int out_size, void* d_ws, size_t ws_size,
                              hipStream_t stream) {
  const float* x    = (const float*)d_in[0];
  const float* Wqkv = (const float*)d_in[1];
  const float* Aqkv = (const float*)d_in[2];
  const float* Bqkv = (const float*)d_in[3];
  const float* Wo   = (const float*)d_in[4];
  const float* Ao   = (const float*)d_in[5];
  const float* Bo   = (const float*)d_in[6];
  const int*   pos  = (const int*)d_in[7];
  float* out = (float*)d_out;
  char* ws = (char*)d_ws;

  u16* xb    = (u16*)(ws + OFF_XB);
  u16* wqkvb = (u16*)(ws + OFF_WQKVB);
  u16* aqkvb = (u16*)(ws + OFF_AQKVB);
  u16* bqkvb = (u16*)(ws + OFF_BQKVB);
  u16* wob   = (u16*)(ws + OFF_WOB);
  u16* aob   = (u16*)(ws + OFF_AOB);
  u16* bob   = (u16*)(ws + OFF_BOB);
  float* qkv = (float*)(ws + OFF_QKV);
  float* tA  = (float*)(ws + OFF_TA);
  u16* tab   = (u16*)(ws + OFF_TAB);
  u16* qb    = (u16*)(ws + OFF_QB);
  u16* kb    = (u16*)(ws + OFF_KB);
  u16* vb    = (u16*)(ws + OFF_VB);
  u16* attnb = (u16*)(ws + OFF_ATTNB);
  float* tO  = (float*)(ws + OFF_TO);
  u16* tob   = (u16*)(ws + OFF_TOB);

  // 1) casts
  launch_cast(x,    xb,    4096 * 3072, stream);
  launch_cast(Wqkv, wqkvb, 5120 * 3072, stream);
  launch_cast(Aqkv, aqkvb, 256 * 3072,  stream);
  launch_cast(Bqkv, bqkvb, 5120 * 256,  stream);
  launch_cast(Wo,   wob,   3072 * 3072, stream);
  launch_cast(Ao,   aob,   256 * 3072,  stream);
  launch_cast(Bo,   bob,   3072 * 256,  stream);

  // 2) qkv = x @ Wqkv^T ; tA = x @ Aqkv^T ; qkv += 2 * tA @ Bqkv^T
  k_gemm_bt<<<dim3(5120 / 64, 4096 / 64), 256, 0, stream>>>(xb, wqkvb, qkv, 4096, 5120, 3072, 1.f, 0);
  k_gemm_bt<<<dim3(256 / 64, 4096 / 64), 256, 0, stream>>>(xb, aqkvb, tA, 4096, 256, 3072, 1.f, 0);
  launch_cast(tA, tab, 4096 * 256, stream);
  k_gemm_bt<<<dim3(5120 / 64, 4096 / 64), 256, 0, stream>>>(tab, bqkvb, qkv, 4096, 5120, 256, 2.0f, 1);

  // 3) rope + split (xb/wqkvb dead from here; qb/kb/vb overlay them)
  k_rope_split<<<dim3(4096, 40), 128, 0, stream>>>(qkv, pos, qb, kb, vb);

  // 4) attention (qkv dead; attnb overlays it)
  k_attn<<<dim3(512, 48), 256, 0, stream>>>(qb, kb, vb, attnb);

  // 5) out = attn @ Wo^T ; tO = attn @ Ao^T ; out += 2 * tO @ Bo^T
  k_gemm_bt<<<dim3(3072 / 64, 4096 / 64), 256, 0, stream>>>(attnb, wob, out, 4096, 3072, 3072, 1.f, 0);
  k_gemm_bt<<<dim3(256 / 64, 4096 / 64), 256, 0, stream>>>(attnb, aob, tO, 4096, 256, 3072, 1.f, 0);
  launch_cast(tO, tob, 4096 * 256, stream);
  k_gemm_bt<<<dim3(3072 / 64, 4096 / 64), 256, 0, stream>>>(tob, bob, out, 4096, 3072, 256, 2.0f, 1);
}

// Round 3
// 1017.557 us; speedup vs baseline: 5.1254x; 5.1254x over previous
//
#include <hip/hip_runtime.h>

typedef unsigned short u16;
typedef unsigned int   u32;

typedef __bf16 bf16_t;
typedef bf16_t bf16x8 __attribute__((ext_vector_type(8)));
typedef float  f32x4  __attribute__((ext_vector_type(4)));
typedef u16    u16x8  __attribute__((ext_vector_type(8)));

__device__ __forceinline__ float bf2f(u16 u) { return __uint_as_float(((u32)u) << 16); }
__device__ __forceinline__ u16 f2bf(float f) {
  u32 u = __float_as_uint(f);
  u32 r = u + 0x7fffu + ((u >> 16) & 1u);
  return (u16)(r >> 16);
}
__device__ __forceinline__ float fast_exp2(float x) { return __builtin_amdgcn_exp2f(x); }

// ---------------- cast f32 -> bf16 ----------------
__global__ void k_cast_bf16(const float* __restrict__ in, u16* __restrict__ out, int n) {
  int i = blockIdx.x * blockDim.x + threadIdx.x;
  int stride = gridDim.x * blockDim.x;
  for (; i < n; i += stride) out[i] = f2bf(in[i]);
}

// ---------------- GEMM: C(MxN) = alpha * A(MxK) @ B(NxK)^T + beta*C ----------------
#define GBM 64
#define GBN 64
#define GBK 64

__global__ __launch_bounds__(256) void k_gemm_bt(
    const u16* __restrict__ A, const u16* __restrict__ B, float* __restrict__ C,
    int M, int N, int K, float alpha, int beta) {
  __shared__ u16 As[GBM][GBK + 8];
  __shared__ u16 Bs[GBN][GBK + 8];
  const int tid   = threadIdx.x;
  const int lane  = tid & 63;
  const int w     = tid >> 6;
  const int wm    = (w >> 1) * 32;
  const int wn    = (w & 1) * 32;
  const int row16 = lane & 15;
  const int quad  = lane >> 4;
  const int m0 = blockIdx.y * GBM;
  const int n0 = blockIdx.x * GBN;
  const int ldr = tid >> 2;
  const int ldc = (tid & 3) * 16;

  f32x4 acc[2][2] = {};

  for (int k0 = 0; k0 < K; k0 += GBK) {
    const u16* ga = A + (size_t)(m0 + ldr) * K + (k0 + ldc);
    const u16* gb = B + (size_t)(n0 + ldr) * K + (k0 + ldc);
    u16x8 a0 = *(const u16x8*)ga;
    u16x8 a1 = *(const u16x8*)(ga + 8);
    u16x8 b0 = *(const u16x8*)gb;
    u16x8 b1 = *(const u16x8*)(gb + 8);
    __syncthreads();
    *(u16x8*)&As[ldr][ldc]     = a0;
    *(u16x8*)&As[ldr][ldc + 8] = a1;
    *(u16x8*)&Bs[ldr][ldc]     = b0;
    *(u16x8*)&Bs[ldr][ldc + 8] = b1;
    __syncthreads();
#pragma unroll
    for (int kk = 0; kk < GBK; kk += 32) {
      bf16x8 af0 = *(const bf16x8*)&As[wm + row16][kk + quad * 8];
      bf16x8 af1 = *(const bf16x8*)&As[wm + 16 + row16][kk + quad * 8];
      bf16x8 bg0 = *(const bf16x8*)&Bs[wn + row16][kk + quad * 8];
      bf16x8 bg1 = *(const bf16x8*)&Bs[wn + 16 + row16][kk + quad * 8];
      acc[0][0] = __builtin_amdgcn_mfma_f32_16x16x32_bf16(af0, bg0, acc[0][0], 0, 0, 0);
      acc[0][1] = __builtin_amdgcn_mfma_f32_16x16x32_bf16(af0, bg1, acc[0][1], 0, 0, 0);
      acc[1][0] = __builtin_amdgcn_mfma_f32_16x16x32_bf16(af1, bg0, acc[1][0], 0, 0, 0);
      acc[1][1] = __builtin_amdgcn_mfma_f32_16x16x32_bf16(af1, bg1, acc[1][1], 0, 0, 0);
    }
  }
#pragma unroll
  for (int tm = 0; tm < 2; ++tm)
#pragma unroll
    for (int tn = 0; tn < 2; ++tn) {
      int gm = m0 + wm + tm * 16 + quad * 4;
      int gn = n0 + wn + tn * 16 + row16;
#pragma unroll
      for (int r = 0; r < 4; ++r) {
        size_t idx = (size_t)(gm + r) * N + gn;
        float v = alpha * acc[tm][tn][r];
        if (beta) v += C[idx];
        C[idx] = v;
      }
    }
}

// ---------------- RoPE + split q,k (v handled by k_vtrans) ----------------
__global__ void k_rope_split(const float* __restrict__ qkv, const int* __restrict__ pos_ids,
                             u16* __restrict__ qb, u16* __restrict__ kb) {
  const int r  = blockIdx.x;   // 0..4095
  const int hh = blockIdx.y;   // 0..31: 0-23 q, 24-31 k
  const int d  = threadIdx.x;  // 0..127
  const float pos = (float)pos_ids[r];
  const float* src;
  if (hh < 24) src = qkv + (size_t)r * 5120 + hh * 128;
  else         src = qkv + (size_t)r * 5120 + 3072 + (hh - 24) * 128;
  float x = src[d];
  float outv;
  if (d >= 96) {
    outv = x;
  } else {
    int j = (d < 48) ? d : d - 48;
    float invf = powf(10000.0f, -(float)j * (1.0f / 48.0f));
    float e = pos * invf;
    float c = cosf(e), sn = sinf(e);
    if (d < 48) outv = x * c - src[d + 48] * sn;
    else        outv = x * c + src[d - 48] * sn;
  }
  u16 o = f2bf(outv);
  if (hh < 24) qb[((size_t)r * 24 + hh) * 128 + d] = o;
  else         kb[((size_t)r * 8 + (hh - 24)) * 128 + d] = o;
}

// ---------------- V transpose: qkv f32 -> vtg bf16 [b][kvh][d][key] ----------------
__global__ void k_vtrans(const float* __restrict__ qkv, u16* __restrict__ vtg) {
  const int d  = threadIdx.x;  // 0..127
  const int kg = blockIdx.x;   // 0..255: 8-key group
  const int bk = blockIdx.y;   // 0..15: b*8 + kvh
  const int b = bk >> 3, kvh = bk & 7;
  const float* src = qkv + (size_t)(b * 2048 + kg * 8) * 5120 + 4096 + kvh * 128 + d;
  u16x8 pack;
#pragma unroll
  for (int t = 0; t < 8; ++t) pack[t] = f2bf(src[(size_t)t * 5120]);
  *(u16x8*)(vtg + ((size_t)bk * 128 + d) * 2048 + kg * 8) = pack;
}

// ---------------- MFMA flash attention (causal, GQA 24q/8kv, D=128) ----------------
// grid (32, 48): x -> q-tile (reversed: heavy blocks first), y = b*24 + h. 4 waves.
#define KS_STRIDE 136  // 128 + 8 (u16)
#define VT_STRIDE 72   // 64 + 8
#define PS_STRIDE 72   // 64 + 8

__global__ __launch_bounds__(256) void k_attn_mfma(
    const u16* __restrict__ qb, const u16* __restrict__ kb, const u16* __restrict__ vtg,
    u16* __restrict__ attnb) {
  __shared__ u16 Ks[64 * KS_STRIDE];      // [key][d]
  __shared__ u16 Vt[128 * VT_STRIDE];     // [d][key]
  __shared__ u16 Ps[4 * 16 * PS_STRIDE];  // per-wave [m][key]

  const int tid   = threadIdx.x;
  const int lane  = tid & 63;
  const int w     = tid >> 6;
  const int row16 = lane & 15;
  const int quad  = lane >> 4;
  const int qt  = (int)gridDim.x - 1 - (int)blockIdx.x;  // heavy tiles first
  const int bh  = blockIdx.y;
  const int b   = bh / 24;
  const int h   = bh % 24;
  const int kvh = h / 3;
  const int q0  = qt * 64;

  // Q fragments in registers: wave strip rows q0 + w*16 + row16
  const u16* qbase = qb + (((size_t)(b * 2048 + q0 + w * 16 + row16)) * 24 + h) * 128;
  bf16x8 qfrag[4];
#pragma unroll
  for (int kk = 0; kk < 4; ++kk) qfrag[kk] = *(const bf16x8*)(qbase + kk * 32 + quad * 8);

  const u16* kbbase = kb + ((size_t)(b * 2048) * 8 + kvh) * 128;
  const u16* vtbase = vtg + (size_t)(b * 8 + kvh) * 128 * 2048;

  f32x4 o[8] = {};
  float mrow[4] = {-INFINITY, -INFINITY, -INFINITY, -INFINITY};
  float lrow[4] = {0.f, 0.f, 0.f, 0.f};
  const float C1 = 0.08838834764831845f * 1.4426950408889634f;  // SCALE * log2(e)

  for (int t = 0; t <= qt; ++t) {
    const int kb0 = t * 64;
    __syncthreads();  // previous tile fully consumed
    // stage K tile: 64 keys x 128 d (straight copy)
#pragma unroll
    for (int i = 0; i < 4; ++i) {
      int c = tid + i * 256;
      int kk = c >> 4, d8 = (c & 15) * 8;
      *(u16x8*)&Ks[kk * KS_STRIDE + d8] =
          *(const u16x8*)(kbbase + (size_t)(kb0 + kk) * (8 * 128) + d8);
    }
    // stage V^T tile: 128 d x 64 keys (straight copy from pre-transposed global)
#pragma unroll
    for (int i = 0; i < 4; ++i) {
      int c = tid + i * 256;
      int d = c >> 3, k8 = (c & 7) * 8;
      *(u16x8*)&Vt[d * VT_STRIDE + k8] =
          *(const u16x8*)(vtbase + (size_t)d * 2048 + kb0 + k8);
    }
    __syncthreads();

    // S = Q K^T  (16x64 per wave)
    f32x4 s[4] = {};
#pragma unroll
    for (int kk = 0; kk < 4; ++kk) {
#pragma unroll
      for (int nt = 0; nt < 4; ++nt) {
        bf16x8 bfr = *(const bf16x8*)&Ks[(nt * 16 + row16) * KS_STRIDE + kk * 32 + quad * 8];
        s[nt] = __builtin_amdgcn_mfma_f32_16x16x32_bf16(qfrag[kk], bfr, s[nt], 0, 0, 0);
      }
    }

    // causal mask on diagonal tile
    if (t == qt) {
#pragma unroll
      for (int nt = 0; nt < 4; ++nt) {
        int col = kb0 + nt * 16 + row16;
#pragma unroll
        for (int r = 0; r < 4; ++r) {
          int row = q0 + w * 16 + quad * 4 + r;
          if (col > row) s[nt][r] = -INFINITY;
        }
      }
    }

    // online softmax per row (rows = quad*4 + r, cols across 16 lanes of the quad)
#pragma unroll
    for (int r = 0; r < 4; ++r) {
      float mx = fmaxf(fmaxf(s[0][r], s[1][r]), fmaxf(s[2][r], s[3][r]));
#pragma unroll
      for (int off = 1; off < 16; off <<= 1) mx = fmaxf(mx, __shfl_xor(mx, off));
      float mnew = fmaxf(mrow[r], mx);
      float alpha = fast_exp2((mrow[r] - mnew) * C1);  // first tile: exp2(-inf)=0
      mrow[r] = mnew;
      float rs = 0.f;
#pragma unroll
      for (int nt = 0; nt < 4; ++nt) {
        float p = fast_exp2((s[nt][r] - mnew) * C1);
        s[nt][r] = p;
        rs += p;
      }
#pragma unroll
      for (int off = 1; off < 16; off <<= 1) rs += __shfl_xor(rs, off);
      lrow[r] = lrow[r] * alpha + rs;
#pragma unroll
      for (int dt = 0; dt < 8; ++dt) o[dt][r] *= alpha;
    }

    // P (C-layout) -> LDS -> A-layout fragments
#pragma unroll
    for (int nt = 0; nt < 4; ++nt)
#pragma unroll
      for (int r = 0; r < 4; ++r)
        Ps[(w * 16 + quad * 4 + r) * PS_STRIDE + nt * 16 + row16] = f2bf(s[nt][r]);
    // wave-synchronous: LDS write->read within the same wave needs no barrier

    // O += P V  (16x128 per wave)
#pragma unroll
    for (int kk2 = 0; kk2 < 2; ++kk2) {
      bf16x8 pa = *(const bf16x8*)&Ps[(w * 16 + row16) * PS_STRIDE + kk2 * 32 + quad * 8];
#pragma unroll
      for (int dt = 0; dt < 8; ++dt) {
        bf16x8 vfr = *(const bf16x8*)&Vt[(dt * 16 + row16) * VT_STRIDE + kk2 * 32 + quad * 8];
        o[dt] = __builtin_amdgcn_mfma_f32_16x16x32_bf16(pa, vfr, o[dt], 0, 0, 0);
      }
    }
  }

  // epilogue: normalize and store bf16
#pragma unroll
  for (int r = 0; r < 4; ++r) {
    float inv = 1.0f / lrow[r];
    int row = q0 + w * 16 + quad * 4 + r;
    size_t obase = ((size_t)(b * 2048 + row)) * 3072 + (size_t)h * 128;
#pragma unroll
    for (int dt = 0; dt < 8; ++dt)
      attnb[obase + dt * 16 + row16] = f2bf(o[dt][r] * inv);
  }
}

// ---------------- workspace layout (bytes) ----------------
#define SZ_XB     ((size_t)4096 * 3072 * 2)
#define SZ_WQKVB  ((size_t)5120 * 3072 * 2)
#define SZ_AQKVB  ((size_t)256 * 3072 * 2)
#define SZ_BQKVB  ((size_t)5120 * 256 * 2)
#define SZ_WOB    ((size_t)3072 * 3072 * 2)
#define SZ_AOB    ((size_t)256 * 3072 * 2)
#define SZ_BOB    ((size_t)3072 * 256 * 2)
#define SZ_QKV    ((size_t)4096 * 5120 * 4)
#define SZ_TA     ((size_t)4096 * 256 * 4)
#define SZ_TAB    ((size_t)4096 * 256 * 2)

#define OFF_XB    ((size_t)0)
#define OFF_WQKVB (OFF_XB + SZ_XB)
#define OFF_AQKVB (OFF_WQKVB + SZ_WQKVB)
#define OFF_BQKVB (OFF_AQKVB + SZ_AQKVB)
#define OFF_WOB   (OFF_BQKVB + SZ_BQKVB)
#define OFF_AOB   (OFF_WOB + SZ_WOB)
#define OFF_BOB   (OFF_AOB + SZ_AOB)
#define OFF_QKV   (OFF_BOB + SZ_BOB)
#define OFF_TA    (OFF_QKV + SZ_QKV)
#define OFF_TAB   (OFF_TA + SZ_TA)
// overlays (lifetimes do not intersect):
#define OFF_QB    OFF_XB                       // qb 25165824 B, overlays dead xb
#define OFF_KB    OFF_WQKVB                    // kb 8388608 B, overlays dead wqkvb
#define OFF_VTG   (OFF_WQKVB + (size_t)8388608) // vtg 8388608 B
#define OFF_ATTNB OFF_QKV                      // attnb overlays dead qkv
#define OFF_TO    (OFF_QKV + (size_t)25165824)
#define OFF_TOB   (OFF_TO + (size_t)4194304)

static inline void launch_cast(const float* in, u16* out, int n, hipStream_t s) {
  int blocks = (n + 1023) / 1024;
  if (blocks > 8192) blocks = 8192;
  k_cast_bf16<<<blocks, 256, 0, s>>>(in, out, n);
}

extern "C" void kernel_launch(void* const* d_in, const int* in_sizes, int n_in,
                              void* d_out, int out_size, void* d_ws, size_t ws_size,
                              hipStream_t stream) {
  const float* x    = (const float*)d_in[0];
  const float* Wqkv = (const float*)d_in[1];
  const float* Aqkv = (const float*)d_in[2];
  const float* Bqkv = (const float*)d_in[3];
  const float* Wo   = (const float*)d_in[4];
  const float* Ao   = (const float*)d_in[5];
  const float* Bo   = (const float*)d_in[6];
  const int*   pos  = (const int*)d_in[7];
  float* out = (float*)d_out;
  char* ws = (char*)d_ws;

  u16* xb    = (u16*)(ws + OFF_XB);
  u16* wqkvb = (u16*)(ws + OFF_WQKVB);
  u16* aqkvb = (u16*)(ws + OFF_AQKVB);
  u16* bqkvb = (u16*)(ws + OFF_BQKVB);
  u16* wob   = (u16*)(ws + OFF_WOB);
  u16* aob   = (u16*)(ws + OFF_AOB);
  u16* bob   = (u16*)(ws + OFF_BOB);
  float* qkv = (float*)(ws + OFF_QKV);
  float* tA  = (float*)(ws + OFF_TA);
  u16* tab   = (u16*)(ws + OFF_TAB);
  u16* qb    = (u16*)(ws + OFF_QB);
  u16* kb    = (u16*)(ws + OFF_KB);
  u16* vtg   = (u16*)(ws + OFF_VTG);
  u16* attnb = (u16*)(ws + OFF_ATTNB);
  float* tO  = (float*)(ws + OFF_TO);
  u16* tob   = (u16*)(ws + OFF_TOB);

  // 1) casts
  launch_cast(x,    xb,    4096 * 3072, stream);
  launch_cast(Wqkv, wqkvb, 5120 * 3072, stream);
  launch_cast(Aqkv, aqkvb, 256 * 3072,  stream);
  launch_cast(Bqkv, bqkvb, 5120 * 256,  stream);
  launch_cast(Wo,   wob,   3072 * 3072, stream);
  launch_cast(Ao,   aob,   256 * 3072,  stream);
  launch_cast(Bo,   bob,   3072 * 256,  stream);

  // 2) qkv = x @ Wqkv^T + 2 * (x @ Aqkv^T) @ Bqkv^T
  k_gemm_bt<<<dim3(5120 / 64, 4096 / 64), 256, 0, stream>>>(xb, wqkvb, qkv, 4096, 5120, 3072, 1.f, 0);
  k_gemm_bt<<<dim3(256 / 64, 4096 / 64), 256, 0, stream>>>(xb, aqkvb, tA, 4096, 256, 3072, 1.f, 0);
  launch_cast(tA, tab, 4096 * 256, stream);
  k_gemm_bt<<<dim3(5120 / 64, 4096 / 64), 256, 0, stream>>>(tab, bqkvb, qkv, 4096, 5120, 256, 2.0f, 1);

  // 3) rope+split q,k ; transpose-cast v (xb/wqkvb dead; qb/kb/vtg overlay)
  k_rope_split<<<dim3(4096, 32), 128, 0, stream>>>(qkv, pos, qb, kb);
  k_vtrans<<<dim3(256, 16), 128, 0, stream>>>(qkv, vtg);

  // 4) MFMA flash attention (qkv dead after vtrans; attnb overlays it)
  k_attn_mfma<<<dim3(32, 48), 256, 0, stream>>>(qb, kb, vtg, attnb);

  // 5) out = attn @ Wo^T + 2 * (attn @ Ao^T) @ Bo^T
  k_gemm_bt<<<dim3(3072 / 64, 4096 / 64), 256, 0, stream>>>(attnb, wob, out, 4096, 3072, 3072, 1.f, 0);
  k_gemm_bt<<<dim3(256 / 64, 4096 / 64), 256, 0, stream>>>(attnb, aob, tO, 4096, 256, 3072, 1.f, 0);
  launch_cast(tO, tob, 4096 * 256, stream);
  k_gemm_bt<<<dim3(3072 / 64, 4096 / 64), 256, 0, stream>>>(tob, bob, out, 4096, 3072, 256, 2.0f, 1);
}